// Round 1
// baseline (8738.241 us; speedup 1.0000x reference)
//
#include <hip/hip_runtime.h>
#include <hip/hip_bf16.h>
#include <math.h>

#define NNODES 100000
#define NEDGES 3200000

// ---------------- init ----------------
__global__ void init_kernel(float* __restrict__ deg, float* __restrict__ smalls) {
    int i = blockIdx.x * 256 + threadIdx.x;
    if (i < NNODES) deg[i] = 1.0f;           // self-loop contribution to degree
    if (i < 592)    smalls[i] = 0.0f;        // keys(8) colsum(8) ata(64) ge(512)
}

__global__ void count_deg_kernel(const int* __restrict__ dst, float* __restrict__ deg) {
    int e = blockIdx.x * 256 + threadIdx.x;
    if (e < NEDGES) atomicAdd(deg + dst[e], 1.0f);
}

__global__ void dinv_kernel(float* __restrict__ deg) {
    int i = blockIdx.x * 256 + threadIdx.x;
    if (i < NNODES) deg[i] = rsqrtf(deg[i]);   // deg >= 1 always
}

// ---------------- generic small-K GEMM: out[N,KOUT] = A[N,KIN] @ W[KIN,KOUT] (+bias, act) ----
// ACT: 0 none, 1 relu, 2 tanh
template <int KIN, int KOUT, int ACT>
__global__ __launch_bounds__(256) void gemm_kernel(const float* __restrict__ A,
                                                   const float* __restrict__ W,
                                                   const float* __restrict__ bias,
                                                   float* __restrict__ out, int nrows) {
    constexpr int ROWS = 1024 / KOUT;      // 256 threads * 4 outputs each
    constexpr int JG   = KOUT / 4;
    __shared__ float As[ROWS][KIN];
    int block_row = blockIdx.x * ROWS;
    int tid = threadIdx.x;

    constexpr int TOT4 = ROWS * KIN / 4;
    const float4* A4 = (const float4*)(A + (size_t)block_row * KIN);
    float4* As4 = (float4*)&As[0][0];
    for (int idx = tid; idx < TOT4; idx += 256) {
        int r = idx / (KIN / 4);
        float4 v = make_float4(0.f, 0.f, 0.f, 0.f);
        if (block_row + r < nrows) v = A4[idx];
        As4[idx] = v;
    }
    __syncthreads();

    int r = tid / JG;
    int j = (tid % JG) * 4;
    float4 acc = make_float4(0.f, 0.f, 0.f, 0.f);
    for (int k = 0; k < KIN; k++) {
        float a = As[r][k];
        float4 w = *(const float4*)(W + (size_t)k * KOUT + j);
        acc.x += a * w.x; acc.y += a * w.y; acc.z += a * w.z; acc.w += a * w.w;
    }
    if (bias) {
        float4 b4 = *(const float4*)(bias + j);
        acc.x += b4.x; acc.y += b4.y; acc.z += b4.z; acc.w += b4.w;
    }
    if (ACT == 1) {
        acc.x = fmaxf(acc.x, 0.f); acc.y = fmaxf(acc.y, 0.f);
        acc.z = fmaxf(acc.z, 0.f); acc.w = fmaxf(acc.w, 0.f);
    } else if (ACT == 2) {
        acc.x = tanhf(acc.x); acc.y = tanhf(acc.y);
        acc.z = tanhf(acc.z); acc.w = tanhf(acc.w);
    }
    if (block_row + r < nrows)
        *(float4*)(out + (size_t)(block_row + r) * KOUT + j) = acc;
}

// ---------------- scale rows by dinv, write two copies (hs and agg-init = self loop) ----
template <int K>
__global__ void scale2_kernel(float* __restrict__ A, float* __restrict__ B,
                              const float* __restrict__ dinv) {
    constexpr int C4 = K / 4;
    size_t idx = (size_t)blockIdx.x * 256 + threadIdx.x;
    size_t total = (size_t)NNODES * C4;
    if (idx >= total) return;
    int row = (int)(idx / C4);
    float d = dinv[row];
    float4 v = ((const float4*)A)[idx];
    v.x *= d; v.y *= d; v.z *= d; v.w *= d;
    ((float4*)A)[idx] = v;
    ((float4*)B)[idx] = v;
}

// ---------------- edge scatter: agg[dst] += hs[src] ----------------
template <int K>
__global__ void scatter_kernel(const int* __restrict__ src, const int* __restrict__ dst,
                               const float* __restrict__ hs, float* __restrict__ agg) {
    constexpr int C4 = K / 4;
    long long g = (long long)blockIdx.x * 256 + threadIdx.x;
    long long total = (long long)NEDGES * C4;
    if (g >= total) return;
    int e = (int)(g / C4);
    int c = (int)(g % C4) * 4;
    int s = src[e], d = dst[e];
    float4 v = *(const float4*)(hs + (size_t)s * K + c);
    float* p = agg + (size_t)d * K + c;
    atomicAdd(p + 0, v.x);
    atomicAdd(p + 1, v.y);
    atomicAdd(p + 2, v.z);
    atomicAdd(p + 3, v.w);
}

// ---------------- out = agg * dinv[row] + bias (optional relu) ----------------
template <int K, bool RELU>
__global__ void finalize_kernel(const float* __restrict__ agg, const float* __restrict__ dinv,
                                const float* __restrict__ bias, float* __restrict__ out) {
    constexpr int C4 = K / 4;
    size_t idx = (size_t)blockIdx.x * 256 + threadIdx.x;
    size_t total = (size_t)NNODES * C4;
    if (idx >= total) return;
    int row = (int)(idx / C4);
    int j = (int)(idx % C4) * 4;
    float d = dinv[row];
    float4 v = ((const float4*)agg)[idx];
    float4 b4 = *(const float4*)(bias + j);
    v.x = v.x * d + b4.x; v.y = v.y * d + b4.y;
    v.z = v.z * d + b4.z; v.w = v.w * d + b4.w;
    if (RELU) {
        v.x = fmaxf(v.x, 0.f); v.y = fmaxf(v.y, 0.f);
        v.z = fmaxf(v.z, 0.f); v.w = fmaxf(v.w, 0.f);
    }
    ((float4*)out)[idx] = v;
}

// ---------------- column max over N for 8 columns (ordered-uint atomicMax) ----------------
__global__ void colmax_kernel(const float* __restrict__ L, unsigned* __restrict__ keys) {
    float m[8];
#pragma unroll
    for (int d = 0; d < 8; d++) m[d] = -INFINITY;
    int stride = gridDim.x * blockDim.x;
    for (int i = blockIdx.x * blockDim.x + threadIdx.x; i < NNODES; i += stride) {
        float4 a = *(const float4*)(L + (size_t)i * 8);
        float4 b = *(const float4*)(L + (size_t)i * 8 + 4);
        m[0] = fmaxf(m[0], a.x); m[1] = fmaxf(m[1], a.y);
        m[2] = fmaxf(m[2], a.z); m[3] = fmaxf(m[3], a.w);
        m[4] = fmaxf(m[4], b.x); m[5] = fmaxf(m[5], b.y);
        m[6] = fmaxf(m[6], b.z); m[7] = fmaxf(m[7], b.w);
    }
#pragma unroll
    for (int off = 32; off > 0; off >>= 1)
#pragma unroll
        for (int d = 0; d < 8; d++) m[d] = fmaxf(m[d], __shfl_down(m[d], off));
    if ((threadIdx.x & 63) == 0) {
#pragma unroll
        for (int d = 0; d < 8; d++) {
            unsigned bits = __float_as_uint(m[d]);
            unsigned key = (bits & 0x80000000u) ? ~bits : (bits | 0x80000000u);
            atomicMax(keys + d, key);
        }
    }
}

// ---------------- exp(L - max) in place, column sums ----------------
__global__ void colsum_kernel(float* __restrict__ L, const unsigned* __restrict__ keys,
                              float* __restrict__ sums) {
    float mx[8];
#pragma unroll
    for (int d = 0; d < 8; d++) {
        unsigned key = keys[d];
        unsigned bits = (key & 0x80000000u) ? (key ^ 0x80000000u) : ~key;
        mx[d] = __uint_as_float(bits);
    }
    float s[8];
#pragma unroll
    for (int d = 0; d < 8; d++) s[d] = 0.f;
    int stride = gridDim.x * blockDim.x;
    for (int i = blockIdx.x * blockDim.x + threadIdx.x; i < NNODES; i += stride) {
        float4 a = *(const float4*)(L + (size_t)i * 8);
        float4 b = *(const float4*)(L + (size_t)i * 8 + 4);
        float v[8] = {a.x, a.y, a.z, a.w, b.x, b.y, b.z, b.w};
#pragma unroll
        for (int d = 0; d < 8; d++) { v[d] = expf(v[d] - mx[d]); s[d] += v[d]; }
        float4 oa = make_float4(v[0], v[1], v[2], v[3]);
        float4 ob = make_float4(v[4], v[5], v[6], v[7]);
        *(float4*)(L + (size_t)i * 8) = oa;
        *(float4*)(L + (size_t)i * 8 + 4) = ob;
    }
#pragma unroll
    for (int off = 32; off > 0; off >>= 1)
#pragma unroll
        for (int d = 0; d < 8; d++) s[d] += __shfl_down(s[d], off);
    if ((threadIdx.x & 63) == 0) {
#pragma unroll
        for (int d = 0; d < 8; d++) atomicAdd(sums + d, s[d]);
    }
}

// ---------------- pooled reductions: ge[8][64] += attU.T@h2 ; ata[8][8] += attU.T@attU ----
__global__ __launch_bounds__(512) void pooled_kernel(const float* __restrict__ att,
                                                     const float* __restrict__ h2,
                                                     float* __restrict__ ge,
                                                     float* __restrict__ ata) {
    __shared__ float attS[64][8];
    __shared__ float h2S[64][64];
    int t = threadIdx.x;
    int d = t >> 6, j = t & 63;
    int de = t >> 3, ee = t & 7;
    float acc = 0.f, acc2 = 0.f;
    int ntiles = (NNODES + 63) / 64;
    for (int tile = blockIdx.x; tile < ntiles; tile += gridDim.x) {
        int base = tile * 64;
        {   // att tile: 512 floats, 1/thread (coalesced)
            int i = t >> 3, c = t & 7;
            int row = base + i;
            attS[i][c] = (row < NNODES) ? att[(size_t)row * 8 + c] : 0.f;
        }
#pragma unroll
        for (int q = 0; q < 2; q++) {   // h2 tile: 1024 float4, 2/thread
            int idx = t + q * 512;
            int i = idx >> 4;
            int c = (idx & 15) * 4;
            int row = base + i;
            float4 v = (row < NNODES) ? *(const float4*)(h2 + (size_t)row * 64 + c)
                                      : make_float4(0.f, 0.f, 0.f, 0.f);
            *(float4*)(&h2S[i][c]) = v;
        }
        __syncthreads();
#pragma unroll 8
        for (int i = 0; i < 64; i++) acc += attS[i][d] * h2S[i][j];
        if (t < 64) {
#pragma unroll 8
            for (int i = 0; i < 64; i++) acc2 += attS[i][de] * attS[i][ee];
        }
        __syncthreads();
    }
    atomicAdd(ge + d * 64 + j, acc);
    if (t < 64) atomicAdd(ata + de * 8 + ee, acc2);
}

// ---------------- tiny epilogue: normalize, penalty, predictions, write d_out ----------------
__global__ void final_kernel(const float* __restrict__ geacc, const float* __restrict__ ata,
                             const float* __restrict__ colsum, const float* __restrict__ Wl,
                             const float* __restrict__ bl, float* __restrict__ out) {
    __shared__ float geF[512];
    __shared__ float inv[8];
    __shared__ float logits[10];
    int t = threadIdx.x;
    if (t < 8) inv[t] = 1.0f / colsum[t];
    __syncthreads();
    for (int idx = t; idx < 512; idx += 64) {
        int d = idx >> 6;
        float v = geacc[idx] * inv[d];
        geF[idx] = v;
        out[idx] = v;                       // graph_embedding
    }
    __syncthreads();
    if (t == 0) {
        float pen = 0.f;
        for (int d = 0; d < 8; d++) {
            float s = 0.f;
            for (int e = 0; e < 8; e++) {
                float p = ata[d * 8 + e] * inv[d] * inv[e] - (d == e ? 1.0f : 0.0f);
                s += p * p;
            }
            pen += sqrtf(s);
        }
        out[512] = pen;                     // penalty
    }
    if (t < 10) {
        float acc = bl[t];
        for (int k = 0; k < 512; k++) acc += geF[k] * Wl[(size_t)k * 10 + t];
        logits[t] = acc;
    }
    __syncthreads();
    if (t == 0) {
        float m = -INFINITY;
        for (int l = 0; l < 10; l++) m = fmaxf(m, logits[l]);
        float s = 0.f;
        for (int l = 0; l < 10; l++) s += expf(logits[l] - m);
        float ls = logf(s);
        for (int l = 0; l < 10; l++) out[513 + l] = logits[l] - m - ls;  // log_softmax
    }
}

extern "C" void kernel_launch(void* const* d_in, const int* in_sizes, int n_in,
                              void* d_out, int out_size, void* d_ws, size_t ws_size,
                              hipStream_t stream) {
    const int* esrc = (const int*)d_in[0];
    const int* edst = esrc + NEDGES;
    const float* X   = (const float*)d_in[1];
    const float* W1  = (const float*)d_in[2];
    const float* b1  = (const float*)d_in[3];
    const float* W2  = (const float*)d_in[4];
    const float* b2  = (const float*)d_in[5];
    const float* Wf1 = (const float*)d_in[6];
    const float* bf1 = (const float*)d_in[7];
    const float* Wf2 = (const float*)d_in[8];
    const float* bf2 = (const float*)d_in[9];
    const float* Wl  = (const float*)d_in[10];
    const float* bl  = (const float*)d_in[11];
    float* out = (float*)d_out;

    // workspace layout (floats)
    float* ws     = (float*)d_ws;
    float* dinv   = ws;                          // N
    float* smalls = ws + NNODES;                 // 592
    unsigned* keys = (unsigned*)smalls;          // 8
    float* colsum = smalls + 8;                  // 8
    float* ata    = smalls + 16;                 // 64
    float* geacc  = smalls + 80;                 // 512
    float* A = ws + NNODES + 1024;               // N*128
    float* B = A + (size_t)NNODES * 128;         // N*128
    float* L = A + (size_t)NNODES * 64;          // N*8 (logits/attU), second half of A
    float* hs2  = B;                             // N*64
    float* agg2 = B + (size_t)NNODES * 64;       // N*64
    float* h2   = B;                             // final h2 (over hs2)
    float* a1   = A;                             // N*64 (over h1)

    const int nblk_n = (NNODES + 255) / 256;

    // degree / dinv
    init_kernel<<<nblk_n, 256, 0, stream>>>(dinv, smalls);
    count_deg_kernel<<<(NEDGES + 255) / 256, 256, 0, stream>>>(edst, dinv);
    dinv_kernel<<<nblk_n, 256, 0, stream>>>(dinv);

    // ---- GCN layer 1 ----
    gemm_kernel<128, 128, 0><<<12500, 256, 0, stream>>>(X, W1, nullptr, A, NNODES);
    scale2_kernel<128><<<12500, 256, 0, stream>>>(A, B, dinv);
    scatter_kernel<128><<<400000, 256, 0, stream>>>(esrc, edst, A, B);
    finalize_kernel<128, true><<<12500, 256, 0, stream>>>(B, dinv, b1, A);   // A = h1

    // ---- GCN layer 2 ----
    gemm_kernel<128, 64, 0><<<6250, 256, 0, stream>>>(A, W2, nullptr, hs2, NNODES);
    scale2_kernel<64><<<6250, 256, 0, stream>>>(hs2, agg2, dinv);
    scatter_kernel<64><<<200000, 256, 0, stream>>>(esrc, edst, hs2, agg2);
    finalize_kernel<64, false><<<6250, 256, 0, stream>>>(agg2, dinv, b2, h2); // B = h2

    // ---- attention head ----
    gemm_kernel<64, 64, 2><<<6250, 256, 0, stream>>>(h2, Wf1, bf1, a1, NNODES);           // tanh
    gemm_kernel<64, 8, 0><<<(NNODES + 127) / 128, 256, 0, stream>>>(a1, Wf2, bf2, L, NNODES);
    colmax_kernel<<<256, 256, 0, stream>>>(L, keys);
    colsum_kernel<<<256, 256, 0, stream>>>(L, keys, colsum);
    pooled_kernel<<<256, 512, 0, stream>>>(L, h2, geacc, ata);
    final_kernel<<<1, 64, 0, stream>>>(geacc, ata, colsum, Wl, bl, out);
}

// Round 2
// 1411.835 us; speedup vs baseline: 6.1893x; 6.1893x over previous
//
#include <hip/hip_runtime.h>
#include <hip/hip_bf16.h>
#include <math.h>

#define NNODES 100000
#define NEDGES 3200000
#define NB ((NNODES + 255) / 256)   // 391 scan blocks

// ---------------- init: zero degree counters + small accumulators ----------------
__global__ void init_kernel(int* __restrict__ cnt, float* __restrict__ smalls) {
    int i = blockIdx.x * 256 + threadIdx.x;
    if (i < NNODES) cnt[i] = 0;
    if (i < 592)    smalls[i] = 0.0f;   // keys(8) colsum(8) ata(64) ge(512)
}

// ---------------- histogram of dst ----------------
__global__ void hist_kernel(const int* __restrict__ dst, int* __restrict__ cnt) {
    int e = blockIdx.x * 256 + threadIdx.x;
    if (e < NEDGES) atomicAdd(cnt + dst[e], 1);
}

// ---------------- dinv = rsqrt(deg+1)  (self loop) ----------------
__global__ void dinv_kernel(const int* __restrict__ cnt, float* __restrict__ dinv) {
    int i = blockIdx.x * 256 + threadIdx.x;
    if (i < NNODES) dinv[i] = rsqrtf((float)cnt[i] + 1.0f);
}

// ---------------- exclusive scan of cnt -> row_start (3 kernels) ----------------
__global__ void scan1_kernel(const int* __restrict__ cnt, int* __restrict__ row_start,
                             int* __restrict__ bsum) {
    __shared__ int s[256];
    int t = threadIdx.x;
    int i = blockIdx.x * 256 + t;
    int v = (i < NNODES) ? cnt[i] : 0;
    s[t] = v;
    __syncthreads();
    for (int off = 1; off < 256; off <<= 1) {
        int x = (t >= off) ? s[t - off] : 0;
        __syncthreads();
        s[t] += x;
        __syncthreads();
    }
    if (i < NNODES) row_start[i] = s[t] - v;     // exclusive within block
    if (t == 255) bsum[blockIdx.x] = s[255];
}

__global__ void scan2_kernel(int* __restrict__ bsum) {
    __shared__ int s[512];
    int t = threadIdx.x;
    int v = (t < NB) ? bsum[t] : 0;
    s[t] = v;
    __syncthreads();
    for (int off = 1; off < 512; off <<= 1) {
        int x = (t >= off) ? s[t - off] : 0;
        __syncthreads();
        s[t] += x;
        __syncthreads();
    }
    if (t < NB) bsum[t] = s[t] - v;              // exclusive block offsets
}

__global__ void scan3_kernel(int* __restrict__ row_start, const int* __restrict__ bsum,
                             int* __restrict__ next) {
    int i = blockIdx.x * 256 + threadIdx.x;
    if (i < NNODES) {
        int rs = row_start[i] + bsum[i >> 8];
        row_start[i] = rs;
        next[i] = rs;                            // fill cursor (aliases cnt)
    }
    if (i == 0) row_start[NNODES] = NEDGES;
}

// ---------------- fill CSR: csr[pos] = src, grouped by dst ----------------
__global__ void fill_kernel(const int* __restrict__ src, const int* __restrict__ dst,
                            int* __restrict__ next, int* __restrict__ csr) {
    int e = blockIdx.x * 256 + threadIdx.x;
    if (e < NEDGES) {
        int pos = atomicAdd(next + dst[e], 1);
        csr[pos] = src[e];
    }
}

// ---------------- generic small-K GEMM: out[N,KOUT] = A[N,KIN] @ W[KIN,KOUT] ----
// optional per-row scale (dinv), bias, activation. ACT: 0 none, 1 relu, 2 tanh
template <int KIN, int KOUT, int ACT>
__global__ __launch_bounds__(256) void gemm_kernel(const float* __restrict__ A,
                                                   const float* __restrict__ W,
                                                   const float* __restrict__ bias,
                                                   const float* __restrict__ rowscale,
                                                   float* __restrict__ out, int nrows) {
    constexpr int ROWS = 1024 / KOUT;      // 256 threads * 4 outputs each
    constexpr int JG   = KOUT / 4;
    __shared__ float As[ROWS][KIN];
    int block_row = blockIdx.x * ROWS;
    int tid = threadIdx.x;

    constexpr int TOT4 = ROWS * KIN / 4;
    const float4* A4 = (const float4*)(A + (size_t)block_row * KIN);
    float4* As4 = (float4*)&As[0][0];
    for (int idx = tid; idx < TOT4; idx += 256) {
        int r = idx / (KIN / 4);
        float4 v = make_float4(0.f, 0.f, 0.f, 0.f);
        if (block_row + r < nrows) v = A4[idx];
        As4[idx] = v;
    }
    __syncthreads();

    int r = tid / JG;
    int j = (tid % JG) * 4;
    float4 acc = make_float4(0.f, 0.f, 0.f, 0.f);
    for (int k = 0; k < KIN; k++) {
        float a = As[r][k];
        float4 w = *(const float4*)(W + (size_t)k * KOUT + j);
        acc.x += a * w.x; acc.y += a * w.y; acc.z += a * w.z; acc.w += a * w.w;
    }
    if (rowscale) {
        float d = rowscale[min(block_row + r, nrows - 1)];
        acc.x *= d; acc.y *= d; acc.z *= d; acc.w *= d;
    }
    if (bias) {
        float4 b4 = *(const float4*)(bias + j);
        acc.x += b4.x; acc.y += b4.y; acc.z += b4.z; acc.w += b4.w;
    }
    if (ACT == 1) {
        acc.x = fmaxf(acc.x, 0.f); acc.y = fmaxf(acc.y, 0.f);
        acc.z = fmaxf(acc.z, 0.f); acc.w = fmaxf(acc.w, 0.f);
    } else if (ACT == 2) {
        acc.x = tanhf(acc.x); acc.y = tanhf(acc.y);
        acc.z = tanhf(acc.z); acc.w = tanhf(acc.w);
    }
    if (block_row + r < nrows)
        *(float4*)(out + (size_t)(block_row + r) * KOUT + j) = acc;
}

// ---------------- gather, K=128: one wave per node, float2 per lane ----------------
// out[n] = relu( (hs[n] + sum_{s in csr[n]} hs[s]) * dinv[n] + bias )
__global__ __launch_bounds__(256) void gather128_kernel(
    const float* __restrict__ hs, const int* __restrict__ row_start,
    const int* __restrict__ csr, const float* __restrict__ dinv,
    const float* __restrict__ bias, float* __restrict__ out) {
    int wave = threadIdx.x >> 6;
    int lane = threadIdx.x & 63;
    int n = blockIdx.x * 4 + wave;
    if (n >= NNODES) return;
    int start = row_start[n], end = row_start[n + 1];
    const float2* h2p = (const float2*)hs;
    size_t selfoff = (size_t)n * 64 + lane;
    float2 acc = h2p[selfoff];                    // self loop (already dinv-scaled)
    int e = start;
    for (; e + 4 <= end; e += 4) {                // 4-deep MLP
        int s0 = csr[e], s1 = csr[e + 1], s2 = csr[e + 2], s3 = csr[e + 3];
        float2 v0 = h2p[(size_t)s0 * 64 + lane];
        float2 v1 = h2p[(size_t)s1 * 64 + lane];
        float2 v2 = h2p[(size_t)s2 * 64 + lane];
        float2 v3 = h2p[(size_t)s3 * 64 + lane];
        acc.x += v0.x + v1.x + v2.x + v3.x;
        acc.y += v0.y + v1.y + v2.y + v3.y;
    }
    for (; e < end; e++) {
        int s = csr[e];
        float2 v = h2p[(size_t)s * 64 + lane];
        acc.x += v.x; acc.y += v.y;
    }
    float d = dinv[n];
    float2 b = ((const float2*)bias)[lane];
    acc.x = fmaxf(acc.x * d + b.x, 0.f);
    acc.y = fmaxf(acc.y * d + b.y, 0.f);
    ((float2*)out)[selfoff] = acc;
}

// ---------------- gather, K=64: one wave per node, 1 float per lane, no relu ----------------
__global__ __launch_bounds__(256) void gather64_kernel(
    const float* __restrict__ hs, const int* __restrict__ row_start,
    const int* __restrict__ csr, const float* __restrict__ dinv,
    const float* __restrict__ bias, float* __restrict__ out) {
    int wave = threadIdx.x >> 6;
    int lane = threadIdx.x & 63;
    int n = blockIdx.x * 4 + wave;
    if (n >= NNODES) return;
    int start = row_start[n], end = row_start[n + 1];
    size_t selfoff = (size_t)n * 64 + lane;
    float acc = hs[selfoff];
    int e = start;
    for (; e + 4 <= end; e += 4) {
        int s0 = csr[e], s1 = csr[e + 1], s2 = csr[e + 2], s3 = csr[e + 3];
        float v0 = hs[(size_t)s0 * 64 + lane];
        float v1 = hs[(size_t)s1 * 64 + lane];
        float v2 = hs[(size_t)s2 * 64 + lane];
        float v3 = hs[(size_t)s3 * 64 + lane];
        acc += v0 + v1 + v2 + v3;
    }
    for (; e < end; e++) acc += hs[(size_t)csr[e] * 64 + lane];
    out[selfoff] = acc * dinv[n] + bias[lane];
}

// ---------------- column max over N for 8 columns (ordered-uint atomicMax) ----------------
__global__ void colmax_kernel(const float* __restrict__ L, unsigned* __restrict__ keys) {
    float m[8];
#pragma unroll
    for (int d = 0; d < 8; d++) m[d] = -INFINITY;
    int stride = gridDim.x * blockDim.x;
    for (int i = blockIdx.x * blockDim.x + threadIdx.x; i < NNODES; i += stride) {
        float4 a = *(const float4*)(L + (size_t)i * 8);
        float4 b = *(const float4*)(L + (size_t)i * 8 + 4);
        m[0] = fmaxf(m[0], a.x); m[1] = fmaxf(m[1], a.y);
        m[2] = fmaxf(m[2], a.z); m[3] = fmaxf(m[3], a.w);
        m[4] = fmaxf(m[4], b.x); m[5] = fmaxf(m[5], b.y);
        m[6] = fmaxf(m[6], b.z); m[7] = fmaxf(m[7], b.w);
    }
#pragma unroll
    for (int off = 32; off > 0; off >>= 1)
#pragma unroll
        for (int d = 0; d < 8; d++) m[d] = fmaxf(m[d], __shfl_down(m[d], off));
    if ((threadIdx.x & 63) == 0) {
#pragma unroll
        for (int d = 0; d < 8; d++) {
            unsigned bits = __float_as_uint(m[d]);
            unsigned key = (bits & 0x80000000u) ? ~bits : (bits | 0x80000000u);
            atomicMax(keys + d, key);
        }
    }
}

// ---------------- exp(L - max) in place, column sums ----------------
__global__ void colsum_kernel(float* __restrict__ L, const unsigned* __restrict__ keys,
                              float* __restrict__ sums) {
    float mx[8];
#pragma unroll
    for (int d = 0; d < 8; d++) {
        unsigned key = keys[d];
        unsigned bits = (key & 0x80000000u) ? (key ^ 0x80000000u) : ~key;
        mx[d] = __uint_as_float(bits);
    }
    float s[8];
#pragma unroll
    for (int d = 0; d < 8; d++) s[d] = 0.f;
    int stride = gridDim.x * blockDim.x;
    for (int i = blockIdx.x * blockDim.x + threadIdx.x; i < NNODES; i += stride) {
        float4 a = *(const float4*)(L + (size_t)i * 8);
        float4 b = *(const float4*)(L + (size_t)i * 8 + 4);
        float v[8] = {a.x, a.y, a.z, a.w, b.x, b.y, b.z, b.w};
#pragma unroll
        for (int d = 0; d < 8; d++) { v[d] = expf(v[d] - mx[d]); s[d] += v[d]; }
        float4 oa = make_float4(v[0], v[1], v[2], v[3]);
        float4 ob = make_float4(v[4], v[5], v[6], v[7]);
        *(float4*)(L + (size_t)i * 8) = oa;
        *(float4*)(L + (size_t)i * 8 + 4) = ob;
    }
#pragma unroll
    for (int off = 32; off > 0; off >>= 1)
#pragma unroll
        for (int d = 0; d < 8; d++) s[d] += __shfl_down(s[d], off);
    if ((threadIdx.x & 63) == 0) {
#pragma unroll
        for (int d = 0; d < 8; d++) atomicAdd(sums + d, s[d]);
    }
}

// ---------------- pooled reductions: ge[8][64] += attU.T@h2 ; ata[8][8] += attU.T@attU ----
__global__ __launch_bounds__(512) void pooled_kernel(const float* __restrict__ att,
                                                     const float* __restrict__ h2,
                                                     float* __restrict__ ge,
                                                     float* __restrict__ ata) {
    __shared__ float attS[64][8];
    __shared__ float h2S[64][64];
    int t = threadIdx.x;
    int d = t >> 6, j = t & 63;
    int de = t >> 3, ee = t & 7;
    float acc = 0.f, acc2 = 0.f;
    int ntiles = (NNODES + 63) / 64;
    for (int tile = blockIdx.x; tile < ntiles; tile += gridDim.x) {
        int base = tile * 64;
        {
            int i = t >> 3, c = t & 7;
            int row = base + i;
            attS[i][c] = (row < NNODES) ? att[(size_t)row * 8 + c] : 0.f;
        }
#pragma unroll
        for (int q = 0; q < 2; q++) {
            int idx = t + q * 512;
            int i = idx >> 4;
            int c = (idx & 15) * 4;
            int row = base + i;
            float4 v = (row < NNODES) ? *(const float4*)(h2 + (size_t)row * 64 + c)
                                      : make_float4(0.f, 0.f, 0.f, 0.f);
            *(float4*)(&h2S[i][c]) = v;
        }
        __syncthreads();
#pragma unroll 8
        for (int i = 0; i < 64; i++) acc += attS[i][d] * h2S[i][j];
        if (t < 64) {
#pragma unroll 8
            for (int i = 0; i < 64; i++) acc2 += attS[i][de] * attS[i][ee];
        }
        __syncthreads();
    }
    atomicAdd(ge + d * 64 + j, acc);
    if (t < 64) atomicAdd(ata + de * 8 + ee, acc2);
}

// ---------------- tiny epilogue ----------------
__global__ void final_kernel(const float* __restrict__ geacc, const float* __restrict__ ata,
                             const float* __restrict__ colsum, const float* __restrict__ Wl,
                             const float* __restrict__ bl, float* __restrict__ out) {
    __shared__ float geF[512];
    __shared__ float inv[8];
    __shared__ float logits[10];
    int t = threadIdx.x;
    if (t < 8) inv[t] = 1.0f / colsum[t];
    __syncthreads();
    for (int idx = t; idx < 512; idx += 64) {
        int d = idx >> 6;
        float v = geacc[idx] * inv[d];
        geF[idx] = v;
        out[idx] = v;                       // graph_embedding
    }
    __syncthreads();
    if (t == 0) {
        float pen = 0.f;
        for (int d = 0; d < 8; d++) {
            float s = 0.f;
            for (int e = 0; e < 8; e++) {
                float p = ata[d * 8 + e] * inv[d] * inv[e] - (d == e ? 1.0f : 0.0f);
                s += p * p;
            }
            pen += sqrtf(s);
        }
        out[512] = pen;                     // penalty
    }
    if (t < 10) {
        float acc = bl[t];
        for (int k = 0; k < 512; k++) acc += geF[k] * Wl[(size_t)k * 10 + t];
        logits[t] = acc;
    }
    __syncthreads();
    if (t == 0) {
        float m = -INFINITY;
        for (int l = 0; l < 10; l++) m = fmaxf(m, logits[l]);
        float s = 0.f;
        for (int l = 0; l < 10; l++) s += expf(logits[l] - m);
        float ls = logf(s);
        for (int l = 0; l < 10; l++) out[513 + l] = logits[l] - m - ls;  // log_softmax
    }
}

extern "C" void kernel_launch(void* const* d_in, const int* in_sizes, int n_in,
                              void* d_out, int out_size, void* d_ws, size_t ws_size,
                              hipStream_t stream) {
    const int* esrc = (const int*)d_in[0];
    const int* edst = esrc + NEDGES;
    const float* X   = (const float*)d_in[1];
    const float* W1  = (const float*)d_in[2];
    const float* b1  = (const float*)d_in[3];
    const float* W2  = (const float*)d_in[4];
    const float* b2  = (const float*)d_in[5];
    const float* Wf1 = (const float*)d_in[6];
    const float* bf1 = (const float*)d_in[7];
    const float* Wf2 = (const float*)d_in[8];
    const float* bf2 = (const float*)d_in[9];
    const float* Wl  = (const float*)d_in[10];
    const float* bl  = (const float*)d_in[11];
    float* out = (float*)d_out;

    // workspace layout
    float* ws     = (float*)d_ws;
    float* dinv   = ws;                               // N (padded to 100352)
    float* smalls = ws + 100352;                      // 1024
    unsigned* keys = (unsigned*)smalls;               // 8
    float* colsum = smalls + 8;                       // 8
    float* ata    = smalls + 16;                      // 64
    float* geacc  = smalls + 80;                      // 512
    float* A = ws + 101376;                           // N*128
    float* B = A + (size_t)NNODES * 128;              // N*128
    int* cnt       = (int*)(B + (size_t)NNODES * 128);// N   (reused as fill cursor)
    int* row_start = cnt + 100352;                    // N+1 (padded)
    int* bsum      = row_start + 100352;              // NB (391, padded to 1024)
    int* csr       = bsum + 1024;                     // E
    float* L  = A + (size_t)NNODES * 64;              // N*8 (attention logits / attU)
    // aliases: h1 -> B ; hs2 -> A ; h2 -> B ; a1 -> A

    const int nblk_n = (NNODES + 255) / 256;   // 391
    const int nblk_e = (NEDGES + 255) / 256;   // 12500

    // ---- CSR build + dinv ----
    init_kernel<<<nblk_n, 256, 0, stream>>>(cnt, smalls);
    hist_kernel<<<nblk_e, 256, 0, stream>>>(edst, cnt);
    dinv_kernel<<<nblk_n, 256, 0, stream>>>(cnt, dinv);
    scan1_kernel<<<NB, 256, 0, stream>>>(cnt, row_start, bsum);
    scan2_kernel<<<1, 512, 0, stream>>>(bsum);
    scan3_kernel<<<nblk_n, 256, 0, stream>>>(row_start, bsum, cnt);
    fill_kernel<<<nblk_e, 256, 0, stream>>>(esrc, edst, cnt, csr);

    // ---- GCN layer 1: A = dinv*(X@W1); h1(B) = relu(gather(A)*dinv + b1) ----
    gemm_kernel<128, 128, 0><<<12500, 256, 0, stream>>>(X, W1, nullptr, dinv, A, NNODES);
    gather128_kernel<<<(NNODES + 3) / 4, 256, 0, stream>>>(A, row_start, csr, dinv, b1, B);

    // ---- GCN layer 2: A = dinv*(h1@W2); h2(B) = gather(A)*dinv + b2 ----
    gemm_kernel<128, 64, 0><<<6250, 256, 0, stream>>>(B, W2, nullptr, dinv, A, NNODES);
    gather64_kernel<<<(NNODES + 3) / 4, 256, 0, stream>>>(A, row_start, csr, dinv, b2, B);

    // ---- attention head ----
    gemm_kernel<64, 64, 2><<<6250, 256, 0, stream>>>(B, Wf1, bf1, nullptr, A, NNODES);     // a1=tanh
    gemm_kernel<64, 8, 0><<<(NNODES + 127) / 128, 256, 0, stream>>>(A, Wf2, bf2, nullptr, L, NNODES);
    colmax_kernel<<<256, 256, 0, stream>>>(L, keys);
    colsum_kernel<<<256, 256, 0, stream>>>(L, keys, colsum);
    pooled_kernel<<<256, 512, 0, stream>>>(L, B, geacc, ata);
    final_kernel<<<1, 64, 0, stream>>>(geacc, ata, colsum, Wl, bl, out);
}